// Round 1
// 1401.669 us; speedup vs baseline: 1.0613x; 1.0613x over previous
//
#include <hip/hip_runtime.h>
#include <hip/hip_bf16.h>

typedef __attribute__((ext_vector_type(8))) short short8;
typedef __attribute__((ext_vector_type(4))) float floatx4;

#define DD 256

__device__ __forceinline__ unsigned short f2bf(float f) {
    unsigned int u = __builtin_bit_cast(unsigned int, f);
    u += 0x7FFFu + ((u >> 16) & 1u);   // round-to-nearest-even
    return (unsigned short)(u >> 16);
}

__device__ __forceinline__ float sigm(float x) { return 1.0f / (1.0f + __expf(-x)); }
__device__ __forceinline__ float tanh_fast(float x) { return 2.0f / (1.0f + __expf(-2.0f * x)) - 1.0f; }

// ---------------- pack weights to bf16, transposed [N][K] ----------------
__global__ void pack_weights(const float* __restrict__ W_f, const float* __restrict__ W_g,
                             unsigned short* __restrict__ WfT, unsigned short* __restrict__ WgT) {
    int idx = blockIdx.x * 256 + threadIdx.x;
    if (idx < 65536) {
        int n = idx >> 8, k = idx & 255;
        WfT[idx] = f2bf(W_f[k * 256 + n]);          // WfT[n][k]
    } else {
        int i2 = idx - 65536;                        // 0..196607
        int n = i2 >> 8, k = i2 & 255;
        WgT[i2] = f2bf(W_g[k * 768 + n]);            // WgT[n][k], n<768
    }
}

// ---------------- CSR offsets from sorted segment_ids ----------------
__global__ void build_start(const int* __restrict__ seg, int E, int P, int* __restrict__ start) {
    int e = blockIdx.x * blockDim.x + threadIdx.x;
    if (e >= E) return;
    int s = seg[e];
    if (e == 0) {
        for (int p = 0; p <= s; ++p) start[p] = 0;
    } else {
        int sp = seg[e - 1];
        for (int p = sp + 1; p <= s; ++p) start[p] = e;
    }
    if (e == E - 1) {
        for (int p = s + 1; p <= P; ++p) start[p] = E;
    }
}

// ---------------- hs_sum: one wave per parent, zero atomics ----------------
__global__ void hs_reduce(const float* __restrict__ child_hs, const int* __restrict__ start,
                          int P, float* __restrict__ hs_sum) {
    int wave = threadIdx.x >> 6, lane = threadIdx.x & 63;
    int p = blockIdx.x * 4 + wave;
    if (p >= P) return;
    int lo = start[p], hi = start[p + 1];
    float4 acc = make_float4(0.f, 0.f, 0.f, 0.f);
    const float4* src = (const float4*)child_hs;
    for (int e = lo; e < hi; ++e) {
        float4 v = src[(size_t)e * 64 + lane];
        acc.x += v.x; acc.y += v.y; acc.z += v.z; acc.w += v.w;
    }
    ((float4*)hs_sum)[(size_t)p * 64 + lane] = acc;
}

// ---------------- GEMM1: F = sigmoid(child_hs @ W_f + b_f); fc += F * child_cs ----------------
// block = 256 thr = 4 waves; M_block = 64 (wave w: rows w*16..+16), N = 256 (16 tiles), K = 256 (8 ksteps)
__global__ __launch_bounds__(256, 2) void gemm1_fc(
    const float* __restrict__ child_hs, const float* __restrict__ child_cs,
    const int* __restrict__ seg, const unsigned short* __restrict__ WfT,
    const float* __restrict__ b_f, float* __restrict__ fc, int E) {
    __shared__ __align__(16) unsigned short ldsB[8192];   // 16 KB: one 32x256 bf16 k-slice, frag-packed
    const int tid = threadIdx.x;
    const int w = tid >> 6, lane = tid & 63;
    const int nl = lane & 15, q = lane >> 4;
    const int e_base = blockIdx.x * 64 + w * 16;

    floatx4 acc[16];
#pragma unroll
    for (int t = 0; t < 16; ++t) acc[t] = (floatx4){0.f, 0.f, 0.f, 0.f};

    const float* Arow = child_hs + (size_t)(e_base + nl) * DD;   // A-frag row m = lane&15

    for (int ks = 0; ks < 8; ++ks) {
        // stage W_f^T k-slice into LDS, packed so frag read = contiguous 16B per lane
#pragma unroll
        for (int r = 0; r < 4; ++r) {
            int chunk = tid + r * 256;                 // 1024 chunks = 256 n-rows x 4 q
            int n = chunk >> 2, qb = chunk & 3;
            uint4 v = *(const uint4*)(WfT + n * 256 + ks * 32 + qb * 8);
            int dst = ((n >> 4) << 6) + (qb << 4) + (n & 15);   // [tile][q][nl]
            ((uint4*)ldsB)[dst] = v;
        }
        // A fragment: 8 consecutive k at k = ks*32 + q*8
        float4 a0 = *(const float4*)(Arow + ks * 32 + q * 8);
        float4 a1 = *(const float4*)(Arow + ks * 32 + q * 8 + 4);
        short8 af;
        af[0] = (short)f2bf(a0.x); af[1] = (short)f2bf(a0.y);
        af[2] = (short)f2bf(a0.z); af[3] = (short)f2bf(a0.w);
        af[4] = (short)f2bf(a1.x); af[5] = (short)f2bf(a1.y);
        af[6] = (short)f2bf(a1.z); af[7] = (short)f2bf(a1.w);
        __syncthreads();
#pragma unroll
        for (int t = 0; t < 16; ++t) {
            short8 bf = ((const short8*)ldsB)[t * 64 + lane];
            acc[t] = __builtin_amdgcn_mfma_f32_16x16x32_bf16(af, bf, acc[t], 0, 0, 0);
        }
        __syncthreads();
    }

    // epilogue: C/D layout col = lane&15 (within tile), row = q*4 + reg
    int e0 = e_base + q * 4;
    int s0 = seg[e0], s1 = seg[e0 + 1], s2 = seg[e0 + 2], s3 = seg[e0 + 3];
#pragma unroll
    for (int t = 0; t < 16; ++t) {
        int n = t * 16 + nl;
        float bias = b_f[n];
        float v0 = sigm(acc[t][0] + bias) * child_cs[(size_t)(e0 + 0) * DD + n];
        float v1 = sigm(acc[t][1] + bias) * child_cs[(size_t)(e0 + 1) * DD + n];
        float v2 = sigm(acc[t][2] + bias) * child_cs[(size_t)(e0 + 2) * DD + n];
        float v3 = sigm(acc[t][3] + bias) * child_cs[(size_t)(e0 + 3) * DD + n];
        // run-combine consecutive equal segments (sorted) -> fewer atomics
        float a = v0; int s = s0;
        if (s1 == s) { a += v1; } else { atomicAdd(&fc[(size_t)s * DD + n], a); a = v1; s = s1; }
        if (s2 == s) { a += v2; } else { atomicAdd(&fc[(size_t)s * DD + n], a); a = v2; s = s2; }
        if (s3 == s) { a += v3; } else { atomicAdd(&fc[(size_t)s * DD + n], a); a = v3; s = s3; }
        atomicAdd(&fc[(size_t)s * DD + n], a);
    }
}

// ---------------- GEMM2: gates = hs_sum @ W_gates + b; fused LSTM epilogue ----------------
// block = 512 thr = 8 waves in 2(row)x4(col) grid; M_block = 64 rows; N = 768; K = 256 (8 ksteps).
// Per k-step the full 768x32 bf16 W-slice (48 KB) is staged into LDS (frag-packed, same layout
// as gemm1) and shared by all 8 waves; each B fragment feeds 2 MFMAs (row-tiles 0/1).
// Wave (wr, wc): rows p_base + wr*32 + {0,16}, cols (wc*4+cgl)*16 + nl for parts i/o/g.
__global__ __launch_bounds__(512, 2) void gemm2_lstm(
    const float* __restrict__ hs_sum, const unsigned short* __restrict__ WgT,
    const float* __restrict__ b_g, float* __restrict__ h_out, float* __restrict__ c_out, int P) {
    __shared__ __align__(16) unsigned short ldsB[24576];   // 48 KB: 768x32 bf16 k-slice, frag-packed
    const int tid = threadIdx.x;
    const int w = tid >> 6, lane = tid & 63;
    const int wr = w >> 2, wc = w & 3;                 // wave row (0..1), wave col (0..3)
    const int nl = lane & 15, q = lane >> 4;
    const int p_base = blockIdx.x * 64;

    floatx4 acc[2][12];
#pragma unroll
    for (int rt = 0; rt < 2; ++rt)
#pragma unroll
        for (int t = 0; t < 12; ++t) acc[rt][t] = (floatx4){0.f, 0.f, 0.f, 0.f};

    // A rows for this wave's two 16-row tiles (OOB rows at grid tail stay inside d_out; their
    // outputs are never written)
    const float* Arow0 = hs_sum + (size_t)(p_base + wr * 32 + nl) * DD;
    const float* Arow1 = Arow0 + (size_t)16 * DD;

    for (int ks = 0; ks < 8; ++ks) {
        // stage WgT k-slice: 3072 chunks of 16B = 48 KB, 6 per thread
#pragma unroll
        for (int r = 0; r < 6; ++r) {
            int chunk = tid + r * 512;                 // 3072 chunks = 768 n-rows x 4 q
            int n = chunk >> 2, qb = chunk & 3;
            uint4 v = *(const uint4*)(WgT + n * 256 + ks * 32 + qb * 8);
            int dst = ((n >> 4) << 6) + (qb << 4) + (n & 15);   // [tile][q][nl]
            ((uint4*)ldsB)[dst] = v;
        }
        // A fragments for both row tiles: 8 consecutive k at k = ks*32 + q*8
        float4 a0 = *(const float4*)(Arow0 + ks * 32 + q * 8);
        float4 a1 = *(const float4*)(Arow0 + ks * 32 + q * 8 + 4);
        float4 a2 = *(const float4*)(Arow1 + ks * 32 + q * 8);
        float4 a3 = *(const float4*)(Arow1 + ks * 32 + q * 8 + 4);
        short8 af0, af1;
        af0[0] = (short)f2bf(a0.x); af0[1] = (short)f2bf(a0.y);
        af0[2] = (short)f2bf(a0.z); af0[3] = (short)f2bf(a0.w);
        af0[4] = (short)f2bf(a1.x); af0[5] = (short)f2bf(a1.y);
        af0[6] = (short)f2bf(a1.z); af0[7] = (short)f2bf(a1.w);
        af1[0] = (short)f2bf(a2.x); af1[1] = (short)f2bf(a2.y);
        af1[2] = (short)f2bf(a2.z); af1[3] = (short)f2bf(a2.w);
        af1[4] = (short)f2bf(a3.x); af1[5] = (short)f2bf(a3.y);
        af1[6] = (short)f2bf(a3.z); af1[7] = (short)f2bf(a3.w);
        __syncthreads();
#pragma unroll
        for (int cgl = 0; cgl < 4; ++cgl) {
#pragma unroll
            for (int part = 0; part < 3; ++part) {
                int t = part * 16 + (wc * 4 + cgl);    // global col-tile in [0,48)
                short8 bf = ((const short8*)ldsB)[t * 64 + lane];
                acc[0][cgl * 3 + part] =
                    __builtin_amdgcn_mfma_f32_16x16x32_bf16(af0, bf, acc[0][cgl * 3 + part], 0, 0, 0);
                acc[1][cgl * 3 + part] =
                    __builtin_amdgcn_mfma_f32_16x16x32_bf16(af1, bf, acc[1][cgl * 3 + part], 0, 0, 0);
            }
        }
        __syncthreads();   // also guarantees all A reads done before epilogue overwrites hs_sum
    }

    // epilogue: C/D layout col = lane&15 (within tile), row = q*4 + reg
#pragma unroll
    for (int rt = 0; rt < 2; ++rt) {
#pragma unroll
        for (int cgl = 0; cgl < 4; ++cgl) {
            int n = (wc * 4 + cgl) * 16 + nl;
            float bi = b_g[n], bo = b_g[256 + n], bg = b_g[512 + n];
#pragma unroll
            for (int reg = 0; reg < 4; ++reg) {
                int p = p_base + wr * 32 + rt * 16 + q * 4 + reg;
                if (p < P) {
                    float I = acc[rt][cgl * 3 + 0][reg] + bi;
                    float O = acc[rt][cgl * 3 + 1][reg] + bo;
                    float G = acc[rt][cgl * 3 + 2][reg] + bg;
                    float iv = sigm(I), ov = sigm(O), gv = tanh_fast(G);
                    float c = iv * gv + c_out[(size_t)p * DD + n];   // c_out currently holds fc
                    float hv = ov * tanh_fast(c);
                    h_out[(size_t)p * DD + n] = hv;
                    c_out[(size_t)p * DD + n] = c;
                }
            }
        }
    }
}

extern "C" void kernel_launch(void* const* d_in, const int* in_sizes, int n_in,
                              void* d_out, int out_size, void* d_ws, size_t ws_size,
                              hipStream_t stream) {
    const float* child_hs = (const float*)d_in[0];
    const float* child_cs = (const float*)d_in[1];
    const int*   seg      = (const int*)d_in[2];
    // d_in[3] = num_segments (device scalar) — P derived from out_size instead
    const float* W_gates  = (const float*)d_in[4];
    const float* b_gates  = (const float*)d_in[5];
    const float* W_f      = (const float*)d_in[6];
    const float* b_f      = (const float*)d_in[7];

    const int D = 256;
    const int E = in_sizes[0] / D;
    const int P = out_size / (2 * D);

    float* h_out = (float*)d_out;                         // doubles as hs_sum accumulator
    float* c_out = (float*)d_out + (size_t)P * D;         // doubles as fc accumulator

    unsigned short* WfT = (unsigned short*)d_ws;          // 65536 bf16
    unsigned short* WgT = WfT + 65536;                    // 196608 bf16
    int* start = (int*)(WgT + 196608);                    // P+1 ints

    // fc accumulator must start at zero (harness poisons d_out)
    hipMemsetAsync(c_out, 0, (size_t)P * D * sizeof(float), stream);

    pack_weights<<<1024, 256, 0, stream>>>(W_f, W_gates, WfT, WgT);
    build_start<<<(E + 255) / 256, 256, 0, stream>>>(seg, E, P, start);
    hs_reduce<<<(P + 3) / 4, 256, 0, stream>>>(child_hs, start, P, h_out);
    gemm1_fc<<<E / 64, 256, 0, stream>>>(child_hs, child_cs, seg, WfT, b_f, c_out, E);
    gemm2_lstm<<<(P + 63) / 64, 512, 0, stream>>>(h_out, WgT, b_gates, h_out, c_out, P);
}

// Round 2
// 1400.861 us; speedup vs baseline: 1.0619x; 1.0006x over previous
//
#include <hip/hip_runtime.h>
#include <hip/hip_bf16.h>

typedef __attribute__((ext_vector_type(8))) short short8;
typedef __attribute__((ext_vector_type(4))) float floatx4;

#define DD 256

__device__ __forceinline__ unsigned short f2bf(float f) {
    unsigned int u = __builtin_bit_cast(unsigned int, f);
    u += 0x7FFFu + ((u >> 16) & 1u);   // round-to-nearest-even
    return (unsigned short)(u >> 16);
}

__device__ __forceinline__ float sigm(float x) { return 1.0f / (1.0f + __expf(-x)); }
__device__ __forceinline__ float tanh_fast(float x) { return 2.0f / (1.0f + __expf(-2.0f * x)) - 1.0f; }

__device__ __forceinline__ short8 pack8(float4 a, float4 b) {
    short8 r;
    r[0] = (short)f2bf(a.x); r[1] = (short)f2bf(a.y);
    r[2] = (short)f2bf(a.z); r[3] = (short)f2bf(a.w);
    r[4] = (short)f2bf(b.x); r[5] = (short)f2bf(b.y);
    r[6] = (short)f2bf(b.z); r[7] = (short)f2bf(b.w);
    return r;
}

// async global->LDS, 16B per lane; LDS dest = uniform base + lane*16 (linear, conflict-free);
// fragment layout achieved by permuting the per-lane GLOBAL source address (m173 pattern)
__device__ __forceinline__ void stage16(const unsigned short* g, unsigned short* l) {
    __builtin_amdgcn_global_load_lds(
        (const __attribute__((address_space(1))) unsigned int*)g,
        (__attribute__((address_space(3))) unsigned int*)l, 16, 0, 0);
}

// ---------------- pack weights to bf16, transposed [N][K] ----------------
__global__ void pack_weights(const float* __restrict__ W_f, const float* __restrict__ W_g,
                             unsigned short* __restrict__ WfT, unsigned short* __restrict__ WgT) {
    int idx = blockIdx.x * 256 + threadIdx.x;
    if (idx < 65536) {
        int n = idx >> 8, k = idx & 255;
        WfT[idx] = f2bf(W_f[k * 256 + n]);          // WfT[n][k]
    } else {
        int i2 = idx - 65536;                        // 0..196607
        int n = i2 >> 8, k = i2 & 255;
        WgT[i2] = f2bf(W_g[k * 768 + n]);            // WgT[n][k], n<768
    }
}

// ---------------- CSR offsets from sorted segment_ids ----------------
__global__ void build_start(const int* __restrict__ seg, int E, int P, int* __restrict__ start) {
    int e = blockIdx.x * blockDim.x + threadIdx.x;
    if (e >= E) return;
    int s = seg[e];
    if (e == 0) {
        for (int p = 0; p <= s; ++p) start[p] = 0;
    } else {
        int sp = seg[e - 1];
        for (int p = sp + 1; p <= s; ++p) start[p] = e;
    }
    if (e == E - 1) {
        for (int p = s + 1; p <= P; ++p) start[p] = E;
    }
}

// ---------------- hs_sum: one wave per parent, zero atomics ----------------
__global__ void hs_reduce(const float* __restrict__ child_hs, const int* __restrict__ start,
                          int P, float* __restrict__ hs_sum) {
    int wave = threadIdx.x >> 6, lane = threadIdx.x & 63;
    int p = blockIdx.x * 4 + wave;
    if (p >= P) return;
    int lo = start[p], hi = start[p + 1];
    float4 acc = make_float4(0.f, 0.f, 0.f, 0.f);
    const float4* src = (const float4*)child_hs;
    for (int e = lo; e < hi; ++e) {
        float4 v = src[(size_t)e * 64 + lane];
        acc.x += v.x; acc.y += v.y; acc.z += v.z; acc.w += v.w;
    }
    ((float4*)hs_sum)[(size_t)p * 64 + lane] = acc;
}

// ---------------- GEMM1: F = sigmoid(child_hs @ W_f + b_f); fc += F * child_cs ----------------
// block = 256 thr = 4 waves; M_block = 64 (wave w: rows w*16..+16), N = 256 (16 tiles), K = 256.
// Double-buffered LDS B-slice staged via global_load_lds (width 16, per-lane permuted source so
// LDS chunk c = [tile=c>>6][q=(c>>4)&3][nl=c&15]); one barrier per k-step; stage(k+1) and the
// A-loads for k+1 are issued before the MFMAs of k so their latency hides under compute.
__global__ __launch_bounds__(256, 2) void gemm1_fc(
    const float* __restrict__ child_hs, const float* __restrict__ child_cs,
    const int* __restrict__ seg, const unsigned short* __restrict__ WfT,
    const float* __restrict__ b_f, float* __restrict__ fc, int E) {
    __shared__ __align__(16) unsigned short ldsB[2][8192];   // 2 x 16 KB k-slices
    const int tid = threadIdx.x;
    const int w = tid >> 6, lane = tid & 63;
    const int nl = lane & 15, q = lane >> 4;
    const int e_base = blockIdx.x * 64 + w * 16;

    floatx4 acc[16];
#pragma unroll
    for (int t = 0; t < 16; ++t) acc[t] = (floatx4){0.f, 0.f, 0.f, 0.f};

    const float* Arow = child_hs + (size_t)(e_base + nl) * DD + q * 8;   // A-frag row m = lane&15
    // staging source for slot (tile = w*4+r, q, nl): WfT + (tile*16+nl)*256 + q*8 + ks*32
    const unsigned short* Wsrc = WfT + ((w * 64 + nl) << 8) + q * 8;

    // prologue: stage ks=0 into buf0, load+pack A(0)
#pragma unroll
    for (int r = 0; r < 4; ++r)
        stage16(Wsrc + (r << 12), &ldsB[0][(w * 4 + r) << 9]);
    float4 a0 = *(const float4*)(Arow);
    float4 a1 = *(const float4*)(Arow + 4);
    short8 af = pack8(a0, a1);
    __syncthreads();

    for (int ks = 0; ks < 8; ++ks) {
        const unsigned short* lcur = ldsB[ks & 1];
        float4 b0, b1;
        if (ks < 7) {
            // issue next k-slice stage + next A loads (async, overlap with MFMAs below)
            unsigned short* lnxt = ldsB[(ks + 1) & 1];
            const unsigned short* ws = Wsrc + (ks + 1) * 32;
#pragma unroll
            for (int r = 0; r < 4; ++r)
                stage16(ws + (r << 12), &lnxt[(w * 4 + r) << 9]);
            b0 = *(const float4*)(Arow + (ks + 1) * 32);
            b1 = *(const float4*)(Arow + (ks + 1) * 32 + 4);
        }
#pragma unroll
        for (int t = 0; t < 16; ++t) {
            short8 bf = ((const short8*)lcur)[t * 64 + lane];
            acc[t] = __builtin_amdgcn_mfma_f32_16x16x32_bf16(af, bf, acc[t], 0, 0, 0);
        }
        if (ks < 7) af = pack8(b0, b1);
        __syncthreads();   // stage(k+1) drained; all reads of buf[cur] done
    }

    // epilogue: C/D layout col = lane&15 (within tile), row = q*4 + reg
    int e0 = e_base + q * 4;
    int s0 = seg[e0], s1 = seg[e0 + 1], s2 = seg[e0 + 2], s3 = seg[e0 + 3];
#pragma unroll
    for (int t = 0; t < 16; ++t) {
        int n = t * 16 + nl;
        float bias = b_f[n];
        float v0 = sigm(acc[t][0] + bias) * child_cs[(size_t)(e0 + 0) * DD + n];
        float v1 = sigm(acc[t][1] + bias) * child_cs[(size_t)(e0 + 1) * DD + n];
        float v2 = sigm(acc[t][2] + bias) * child_cs[(size_t)(e0 + 2) * DD + n];
        float v3 = sigm(acc[t][3] + bias) * child_cs[(size_t)(e0 + 3) * DD + n];
        // run-combine consecutive equal segments (sorted) -> fewer atomics
        float a = v0; int s = s0;
        if (s1 == s) { a += v1; } else { atomicAdd(&fc[(size_t)s * DD + n], a); a = v1; s = s1; }
        if (s2 == s) { a += v2; } else { atomicAdd(&fc[(size_t)s * DD + n], a); a = v2; s = s2; }
        if (s3 == s) { a += v3; } else { atomicAdd(&fc[(size_t)s * DD + n], a); a = v3; s = s3; }
        atomicAdd(&fc[(size_t)s * DD + n], a);
    }
}

// ---------------- GEMM2: gates = hs_sum @ W_gates + b; fused LSTM epilogue ----------------
// block = 512 thr = 8 waves in 2(row)x4(col) grid; M_block = 64 rows; N = 768; K = 256.
// Single 48 KB LDS k-slice staged via global_load_lds (same permuted-source layout);
// stage(k+1) issued right after the read-done barrier so it overlaps next iter's A loads.
__global__ __launch_bounds__(512, 2) void gemm2_lstm(
    const float* __restrict__ hs_sum, const unsigned short* __restrict__ WgT,
    const float* __restrict__ b_g, float* __restrict__ h_out, float* __restrict__ c_out, int P) {
    __shared__ __align__(16) unsigned short ldsB[24576];   // 48 KB: 768x32 bf16 k-slice
    const int tid = threadIdx.x;
    const int w = tid >> 6, lane = tid & 63;
    const int wr = w >> 2, wc = w & 3;                 // wave row (0..1), wave col (0..3)
    const int nl = lane & 15, q = lane >> 4;
    const int p_base = blockIdx.x * 64;

    floatx4 acc[2][12];
#pragma unroll
    for (int rt = 0; rt < 2; ++rt)
#pragma unroll
        for (int t = 0; t < 12; ++t) acc[rt][t] = (floatx4){0.f, 0.f, 0.f, 0.f};

    const float* Arow0 = hs_sum + (size_t)(p_base + wr * 32 + nl) * DD + q * 8;
    const float* Arow1 = Arow0 + (size_t)16 * DD;
    // staging source for slot (tile = w*6+r, q, nl)
    const unsigned short* Wsrc = WgT + ((w * 96 + nl) << 8) + q * 8;

    // prologue: stage ks=0
#pragma unroll
    for (int r = 0; r < 6; ++r)
        stage16(Wsrc + (r << 12), &ldsB[(w * 6 + r) << 9]);

    for (int ks = 0; ks < 8; ++ks) {
        // A loads overlap with the stage still in flight
        float4 a0 = *(const float4*)(Arow0 + ks * 32);
        float4 a1 = *(const float4*)(Arow0 + ks * 32 + 4);
        float4 a2 = *(const float4*)(Arow1 + ks * 32);
        float4 a3 = *(const float4*)(Arow1 + ks * 32 + 4);
        short8 af0 = pack8(a0, a1);
        short8 af1 = pack8(a2, a3);
        __syncthreads();   // stage(ks) complete
#pragma unroll
        for (int cgl = 0; cgl < 4; ++cgl) {
#pragma unroll
            for (int part = 0; part < 3; ++part) {
                int t = part * 16 + (wc * 4 + cgl);    // global col-tile in [0,48)
                short8 bf = ((const short8*)ldsB)[t * 64 + lane];
                acc[0][cgl * 3 + part] =
                    __builtin_amdgcn_mfma_f32_16x16x32_bf16(af0, bf, acc[0][cgl * 3 + part], 0, 0, 0);
                acc[1][cgl * 3 + part] =
                    __builtin_amdgcn_mfma_f32_16x16x32_bf16(af1, bf, acc[1][cgl * 3 + part], 0, 0, 0);
            }
        }
        __syncthreads();   // all reads done (also fences A reads before epilogue overwrites hs_sum)
        if (ks < 7) {
            const unsigned short* ws = Wsrc + (ks + 1) * 32;
#pragma unroll
            for (int r = 0; r < 6; ++r)
                stage16(ws + (r << 12), &ldsB[(w * 6 + r) << 9]);
        }
    }

    // epilogue: C/D layout col = lane&15 (within tile), row = q*4 + reg
#pragma unroll
    for (int rt = 0; rt < 2; ++rt) {
#pragma unroll
        for (int cgl = 0; cgl < 4; ++cgl) {
            int n = (wc * 4 + cgl) * 16 + nl;
            float bi = b_g[n], bo = b_g[256 + n], bg = b_g[512 + n];
#pragma unroll
            for (int reg = 0; reg < 4; ++reg) {
                int p = p_base + wr * 32 + rt * 16 + q * 4 + reg;
                if (p < P) {
                    float I = acc[rt][cgl * 3 + 0][reg] + bi;
                    float O = acc[rt][cgl * 3 + 1][reg] + bo;
                    float G = acc[rt][cgl * 3 + 2][reg] + bg;
                    float iv = sigm(I), ov = sigm(O), gv = tanh_fast(G);
                    float c = iv * gv + c_out[(size_t)p * DD + n];   // c_out currently holds fc
                    float hv = ov * tanh_fast(c);
                    h_out[(size_t)p * DD + n] = hv;
                    c_out[(size_t)p * DD + n] = c;
                }
            }
        }
    }
}

extern "C" void kernel_launch(void* const* d_in, const int* in_sizes, int n_in,
                              void* d_out, int out_size, void* d_ws, size_t ws_size,
                              hipStream_t stream) {
    const float* child_hs = (const float*)d_in[0];
    const float* child_cs = (const float*)d_in[1];
    const int*   seg      = (const int*)d_in[2];
    // d_in[3] = num_segments (device scalar) — P derived from out_size instead
    const float* W_gates  = (const float*)d_in[4];
    const float* b_gates  = (const float*)d_in[5];
    const float* W_f      = (const float*)d_in[6];
    const float* b_f      = (const float*)d_in[7];

    const int D = 256;
    const int E = in_sizes[0] / D;
    const int P = out_size / (2 * D);

    float* h_out = (float*)d_out;                         // doubles as hs_sum accumulator
    float* c_out = (float*)d_out + (size_t)P * D;         // doubles as fc accumulator

    unsigned short* WfT = (unsigned short*)d_ws;          // 65536 bf16
    unsigned short* WgT = WfT + 65536;                    // 196608 bf16
    int* start = (int*)(WgT + 196608);                    // P+1 ints

    // fc accumulator must start at zero (harness poisons d_out)
    hipMemsetAsync(c_out, 0, (size_t)P * D * sizeof(float), stream);

    pack_weights<<<1024, 256, 0, stream>>>(W_f, W_gates, WfT, WgT);
    build_start<<<(E + 255) / 256, 256, 0, stream>>>(seg, E, P, start);
    hs_reduce<<<(P + 3) / 4, 256, 0, stream>>>(child_hs, start, P, h_out);
    gemm1_fc<<<E / 64, 256, 0, stream>>>(child_hs, child_cs, seg, WfT, b_f, c_out, E);
    gemm2_lstm<<<(P + 63) / 64, 512, 0, stream>>>(h_out, WgT, b_gates, h_out, c_out, P);
}